// Round 2
// baseline (1262.797 us; speedup 1.0000x reference)
//
#include <hip/hip_runtime.h>
#include <math.h>

#define T_LEN 4096
#define C_LEN 256
#define B_LEN 16
#define LOG2E 1.4426950408889634f
#define HSTR 80   // H-buffer row stride in bytes (16B-aligned, non-pow2 banking)

// ---------------------------------------------------------------------------
// Compile-time Gaussian kernel bank (matches numpy: exp(-0.5*(j/s)^2), trunc
// at r=int(4*s), normalized by sum+1e-12). Values become instruction literals.
// ---------------------------------------------------------------------------
constexpr double cexp(double x) {
    double y = x * (1.0 / 1024.0);
    double t = 1.0, term = 1.0;
    for (int i = 1; i <= 12; ++i) { term *= y / i; t += term; }
    for (int i = 0; i < 10; ++i) t = t * t;   // ^1024
    return t;
}

constexpr int RAD[5] = {10, 16, 24, 36, 56};

struct Bank { float g[5][57]; };

constexpr Bank make_bank() {
    Bank b{};
    const double sig[5] = {2.5, 4.0, 6.0, 9.0, 14.0};
    for (int k = 0; k < 5; ++k) {
        double w[57] = {};
        for (int j = 0; j <= RAD[k]; ++j)
            w[j] = cexp(-0.5 * (double)(j * j) / (sig[k] * sig[k]));
        double s = w[0];
        for (int j = 1; j <= RAD[k]; ++j) s += 2.0 * w[j];
        s += 1e-12;
        for (int j = 0; j <= RAD[k]; ++j) b.g[k][j] = (float)(w[j] / s);
    }
    return b;
}

constexpr Bank BANK = make_bank();

typedef _Float16 hf;
typedef hf    hfx2 __attribute__((ext_vector_type(2)));
typedef hf    hfx8 __attribute__((ext_vector_type(8)));
typedef float f32x4 __attribute__((ext_vector_type(4)));

// Compiler-level memory fence (no instruction emitted). Needed because the
// MLP phase communicates across lanes through per-wave LDS with no barriers:
// hardware DS ops are in-order per wave, but the compiler must not reorder.
__device__ __forceinline__ void lds_fence() { asm volatile("" ::: "memory"); }

__device__ __forceinline__ float fast_exp2(float x) {
#if __has_builtin(__builtin_amdgcn_exp2f)
    return __builtin_amdgcn_exp2f(x);
#else
    return __expf(x * 0.6931471805599453f);
#endif
}

// ---------------------------------------------------------------------------
// Fast GELU (tanh form): x * sigmoid(1.5957691216*(x + 0.044715 x^3)).
// ---------------------------------------------------------------------------
__device__ __forceinline__ float gelu_fast(float v) {
    const float c1 = (float)(-2.0 * 0.7978845608028654 * 1.4426950408889634);
    const float c2 = c1 * 0.044715f;
    float v2 = v * v;
    float t  = fmaf(c2, v2, c1);
    float z  = v * t;
    float e  = fast_exp2(z);
    float r  = __builtin_amdgcn_rcpf(1.0f + e);
    return v * r;
}

__device__ __forceinline__ float ldz(const float* __restrict__ xb, int tt) {
    if (tt < 0 || tt >= T_LEN) return 0.0f;
    return xb[tt * C_LEN];
}

// ---------------------------------------------------------------------------
// Per-lane MFMA weight fragments for the conditioner MLP.
// Layer1 (K=32, k0..3 = [W1 rows 0..2, b1], rest zero):
//   b1a = hidden 0..15, b1b = hidden 16..31 (B-operand: col = lane&15,
//   k = 8*(lane>>4)+j — the standard CDNA4 16x16x32 B layout).
// Layer2: W2's K-rows permuted to the interleaved hidden order
//   canon(kk) = (kk&1)*16 + (kk>>1) so the gelu pack (h[n], h[n+16]) lands
//   as adjacent f16s in the H LDS rows. W2/b2 pre-scaled by LOG2E so the
//   softmax uses raw v_exp_f32.
// wraw layout: [0..95] W1(3x32), [96..127] b1, [128..287] W2(32x5), [288..292] b2
// ---------------------------------------------------------------------------
struct Frags { hfx8 b1a, b1b, b2; f32x4 c2; };

__device__ __forceinline__ Frags build_frags(const float* __restrict__ wraw, int lane) {
    Frags f;
    const int n = lane & 15, g = lane >> 4;
    hfx8 z = {0, 0, 0, 0, 0, 0, 0, 0};
    f.b1a = z; f.b1b = z;
    if (g == 0) {
        f.b1a[0] = (hf)wraw[n];      f.b1b[0] = (hf)wraw[16 + n];
        f.b1a[1] = (hf)wraw[32 + n]; f.b1b[1] = (hf)wraw[48 + n];
        f.b1a[2] = (hf)wraw[64 + n]; f.b1b[2] = (hf)wraw[80 + n];
        f.b1a[3] = (hf)wraw[96 + n]; f.b1b[3] = (hf)wraw[112 + n];
    }
#pragma unroll
    for (int j = 0; j < 8; ++j) {
        int kk = 8 * g + j;
        int canon = ((kk & 1) << 4) | (kk >> 1);
        float wv = (n < 5) ? wraw[128 + canon * 5 + n] * LOG2E : 0.0f;
        f.b2[j] = (hf)wv;
    }
    float cc = (n < 5) ? wraw[288 + n] * LOG2E : 0.0f;
    f.c2 = (f32x4){cc, cc, cc, cc};
    return f;
}

// ---------------------------------------------------------------------------
// Per-thread worker: one channel c, 4 consecutive t starting at t0.
// CHECKED=true handles series edges (zero-pad conv, reflect-pad pooling).
// Position id within a wave: p = m*64 + lane  (tile = p>>4, row = p&15).
// fe: 4KB per-wave LDS; 256 rows x 16B. Rows hold the A-operand feats
//     [mean, var, x, 1, 0...] f16; later overwritten per-tile by the 5 f16
//     logits (safe: tile-t rows are consumed by layer1 before layer2 writes).
// hb: per-wave LDS H buffer; 16 rows x HSTR bytes (64B payload), reused/tile.
// All LDS traffic is wave-private -> no barriers; DS ops are in-order/wave;
// lds_fence() stops compiler reordering at the cross-lane hand-off points.
// ---------------------------------------------------------------------------
template <bool CHECKED>
__device__ __forceinline__ void work(const float* __restrict__ x,
                                     float* __restrict__ out,
                                     const float* __restrict__ wraw,
                                     char* __restrict__ fe,
                                     char* __restrict__ hb,
                                     int b, int t0, int c, int lane) {
    const float* xb = x + (size_t)b * T_LEN * C_LEN + c;  // index by t*C_LEN

    // ---- pooling window values: x[t0-7 .. t0+11] (reflect at edges) ----
    float v[19];
#pragma unroll
    for (int i = 0; i < 19; ++i) {
        int tt = t0 - 7 + i;
        if (CHECKED) {
            tt = (tt < 0) ? -tt : tt;
            tt = (tt >= T_LEN) ? (2 * T_LEN - 2 - tt) : tt;
        }
        v[i] = xb[tt * C_LEN];
    }

    float mean[4], var[4], xc[4];
    {
        float s = 0.f, q = 0.f;
#pragma unroll
        for (int i = 0; i < 16; ++i) { s += v[i]; q = fmaf(v[i], v[i], q); }
#pragma unroll
        for (int m = 0; m < 4; ++m) {
            if (m > 0) {
                float nw = v[15 + m], od = v[m - 1];
                s = s + nw - od;
                q = fmaf(nw, nw, fmaf(od, -od, q));
            }
            mean[m] = s * 0.0625f;
            float m2 = q * 0.0625f;
            float vv = fmaf(-mean[m], mean[m], m2);
            var[m] = vv > 0.f ? vv : 0.f;
            xc[m]  = v[7 + m];
        }
    }

    // ---- stage feats rows into LDS (A-operand for layer1) ----
#pragma unroll
    for (int m = 0; m < 4; ++m) {
        auto p0 = __builtin_amdgcn_cvt_pkrtz(mean[m], var[m]);
        auto p1 = __builtin_amdgcn_cvt_pkrtz(xc[m], 1.0f);
        int4 r4;
        r4.x = __builtin_bit_cast(int, p0);
        r4.y = __builtin_bit_cast(int, p1);
        r4.z = 0; r4.w = 0;
        *(int4*)(fe + (m * 64 + lane) * 16) = r4;
    }
    lds_fence();

    // ---- 5 Gaussian convs, symmetric-pair register sliding windows ----
    float acc[5][4];
#pragma unroll
    for (int k = 0; k < 5; ++k)
#pragma unroll
        for (int m = 0; m < 4; ++m) acc[k][m] = BANK.g[k][0] * xc[m];

    float F[4], Bw[4];
    if (CHECKED) {
        F[1] = ldz(xb, t0 + 1); F[2] = ldz(xb, t0 + 2);
        F[3] = ldz(xb, t0 + 3); F[0] = ldz(xb, t0 + 4);
        Bw[3] = ldz(xb, t0 - 1); Bw[0] = ldz(xb, t0);
        Bw[1] = ldz(xb, t0 + 1); Bw[2] = ldz(xb, t0 + 2);
    } else {
        F[1] = v[8]; F[2] = v[9]; F[3] = v[10]; F[0] = v[11];
        Bw[3] = v[6]; Bw[0] = v[7]; Bw[1] = v[8]; Bw[2] = v[9];
    }

#pragma unroll
    for (int j = 1; j <= 56; ++j) {
        float sm[4];
#pragma unroll
        for (int m = 0; m < 4; ++m)
            sm[m] = F[(j + m) & 3] + Bw[(m - j) & 3];
#pragma unroll
        for (int k = 0; k < 5; ++k) {
            if (j <= RAD[k]) {
#pragma unroll
                for (int m = 0; m < 4; ++m)
                    acc[k][m] = fmaf(BANK.g[k][j], sm[m], acc[k][m]);
            }
        }
        if (j < 56) {
            if (CHECKED) {
                F[j & 3]        = ldz(xb, t0 + j + 4);
                Bw[(3 - j) & 3] = ldz(xb, t0 - j - 1);
            } else {
                F[j & 3]        = (j <= 7) ? v[j + 11] : xb[(t0 + j + 4) * C_LEN];
                Bw[(3 - j) & 3] = (j <= 6) ? v[6 - j]  : xb[(t0 - j - 1) * C_LEN];
            }
        }
    }

    // ---- conditioner MLP on the matrix pipe: 16 tiles of 16 positions ----
    // Per tile: A1 read -> 2x mfma (layer1) -> gelu x8 -> pack to H ->
    //           A2 read -> 1x mfma (layer2, +b2*LOG2E via C) -> f16 logits.
    // Frags built here (after conv) so conv-phase VGPR peak is unchanged.
    Frags fr = build_frags(wraw, lane);
    const int rl = lane & 15, gq = lane >> 4;
    const char* a1p = fe + rl * 16;                     // + t*256 per tile
    char*       hwp = hb + gq * (4 * HSTR) + rl * 4;    // + r*HSTR per row
    const char* a2p = hb + rl * HSTR + gq * 16;
    char*       lwp = fe + gq * 64 + rl * 2;            // + t*256 + r*16 (rl<5)
    const f32x4 z4 = (f32x4){0.f, 0.f, 0.f, 0.f};

#pragma unroll 2
    for (int t = 0; t < 16; ++t) {
        hfx8 a1 = *(const hfx8*)(a1p + t * 256);
        f32x4 d1a = __builtin_amdgcn_mfma_f32_16x16x32_f16(a1, fr.b1a, z4, 0, 0, 0);
        f32x4 d1b = __builtin_amdgcn_mfma_f32_16x16x32_f16(a1, fr.b1b, z4, 0, 0, 0);
#pragma unroll
        for (int r = 0; r < 4; ++r) {
            auto hp = __builtin_amdgcn_cvt_pkrtz(gelu_fast(d1a[r]), gelu_fast(d1b[r]));
            *(int*)(hwp + r * HSTR) = __builtin_bit_cast(int, hp);
        }
        lds_fence();
        hfx8 a2 = *(const hfx8*)a2p;
        lds_fence();
        f32x4 d2 = __builtin_amdgcn_mfma_f32_16x16x32_f16(a2, fr.b2, fr.c2, 0, 0, 0);
        if (rl < 5) {
#pragma unroll
            for (int r = 0; r < 4; ++r)
                *(hf*)(lwp + t * 256 + r * 16) = (hf)d2[r];
        }
    }
    lds_fence();

    // ---- readback logits + softmax over K=5 (already x LOG2E; max-free:
    // |logit*log2e| is bounded << 127 so exp2 can't overflow) + mixture ----
#pragma unroll
    for (int m = 0; m < 4; ++m) {
        const char* Lr = fe + (m * 64 + lane) * 16;
        hfx2 q01 = *(const hfx2*)(Lr);
        hfx2 q23 = *(const hfx2*)(Lr + 4);
        hf   q4  = *(const hf*)(Lr + 8);
        float e0 = fast_exp2((float)q01[0]);
        float e1 = fast_exp2((float)q01[1]);
        float e2 = fast_exp2((float)q23[0]);
        float e3 = fast_exp2((float)q23[1]);
        float e4 = fast_exp2((float)q4);
        float den = ((e0 + e1) + (e2 + e3)) + e4;
        float num = e0 * acc[0][m];
        num = fmaf(e1, acc[1][m], num);
        num = fmaf(e2, acc[2][m], num);
        num = fmaf(e3, acc[3][m], num);
        num = fmaf(e4, acc[4][m], num);
        out[((size_t)b * T_LEN + t0 + m) * C_LEN + c] = num * __builtin_amdgcn_rcpf(den);
    }
}

// ---------------------------------------------------------------------------
// Single fused kernel. Boundary chunks (28/1024 per b) take the CHECKED path.
// Raw weights staged once to LDS (one __syncthreads); per-wave FE/H buffers
// need no further barriers.
// BUGFIX (round 1): weight staging must cover 293 words with 256 threads —
// the one-element-per-thread version left wraw[256..292] (W2 rows 25..31 and
// all of b2) uninitialized -> NaN logits.
// ---------------------------------------------------------------------------
__global__ __launch_bounds__(256, 4) void agt_fused(
    const float* __restrict__ x, const float* __restrict__ W1,
    const float* __restrict__ b1, const float* __restrict__ W2,
    const float* __restrict__ b2, float* __restrict__ out) {
    __shared__ float wraw[296];
    __shared__ __align__(16) char fe_lds[4][4096];
    __shared__ __align__(16) char h_lds[4][16 * HSTR];

    int tid = threadIdx.x;
    for (int i = tid; i < 293; i += 256) {
        float w;
        if (i < 96)       w = W1[i];
        else if (i < 128) w = b1[i - 96];
        else if (i < 288) w = W2[i - 128];
        else              w = b2[i - 288];
        wraw[i] = w;
    }
    __syncthreads();

    int b     = blockIdx.x >> 10;        // 1024 chunks per batch
    int chunk = blockIdx.x & 1023;
    int t0    = chunk * 4;
    int lane  = tid & 63;
    char* fe  = &fe_lds[tid >> 6][0];
    char* hb  = &h_lds[tid >> 6][0];

    if (chunk >= 14 && chunk < 1010)
        work<false>(x, out, wraw, fe, hb, b, t0, tid, lane);
    else
        work<true>(x, out, wraw, fe, hb, b, t0, tid, lane);
}

extern "C" void kernel_launch(void* const* d_in, const int* in_sizes, int n_in,
                              void* d_out, int out_size, void* d_ws, size_t ws_size,
                              hipStream_t stream) {
    const float* x  = (const float*)d_in[0];
    const float* W1 = (const float*)d_in[1];
    const float* b1 = (const float*)d_in[2];
    const float* W2 = (const float*)d_in[3];
    const float* b2 = (const float*)d_in[4];
    float* out = (float*)d_out;

    (void)in_sizes; (void)n_in; (void)d_ws; (void)ws_size; (void)out_size;

    agt_fused<<<dim3(B_LEN * 1024), dim3(256), 0, stream>>>(x, W1, b1, W2, b2, out);
}

// Round 3
// 462.418 us; speedup vs baseline: 2.7309x; 2.7309x over previous
//
#include <hip/hip_runtime.h>
#include <math.h>

#define T_LEN 4096
#define C_LEN 256
#define B_LEN 16
#define LOG2E 1.4426950408889634f
#define HSTR 80   // H-buffer row stride in bytes (16B-aligned, non-pow2 banking)
#define LSTR 12   // logit buffer stride per position (bank = 3*pos % 32 -> 2-way)

// ---------------------------------------------------------------------------
// Compile-time Gaussian kernel bank (matches numpy: exp(-0.5*(j/s)^2), trunc
// at r=int(4*s), normalized by sum+1e-12). Values become instruction literals.
// ---------------------------------------------------------------------------
constexpr double cexp(double x) {
    double y = x * (1.0 / 1024.0);
    double t = 1.0, term = 1.0;
    for (int i = 1; i <= 12; ++i) { term *= y / i; t += term; }
    for (int i = 0; i < 10; ++i) t = t * t;   // ^1024
    return t;
}

constexpr int RAD[5] = {10, 16, 24, 36, 56};

struct Bank { float g[5][57]; };

constexpr Bank make_bank() {
    Bank b{};
    const double sig[5] = {2.5, 4.0, 6.0, 9.0, 14.0};
    for (int k = 0; k < 5; ++k) {
        double w[57] = {};
        for (int j = 0; j <= RAD[k]; ++j)
            w[j] = cexp(-0.5 * (double)(j * j) / (sig[k] * sig[k]));
        double s = w[0];
        for (int j = 1; j <= RAD[k]; ++j) s += 2.0 * w[j];
        s += 1e-12;
        for (int j = 0; j <= RAD[k]; ++j) b.g[k][j] = (float)(w[j] / s);
    }
    return b;
}

constexpr Bank BANK = make_bank();

typedef _Float16 hf;
typedef hf    hfx2 __attribute__((ext_vector_type(2)));
typedef hf    hfx8 __attribute__((ext_vector_type(8)));
typedef float f32x4 __attribute__((ext_vector_type(4)));

// Compiler-level memory fence (no instruction emitted). Needed because the
// MLP phase communicates across lanes through per-wave LDS with no barriers:
// hardware DS ops are in-order per wave, but the compiler must not reorder.
__device__ __forceinline__ void lds_fence() { asm volatile("" ::: "memory"); }

__device__ __forceinline__ float fast_exp2(float x) {
#if __has_builtin(__builtin_amdgcn_exp2f)
    return __builtin_amdgcn_exp2f(x);
#else
    return __expf(x * 0.6931471805599453f);
#endif
}

// ---------------------------------------------------------------------------
// Fast GELU (tanh form): x * sigmoid(1.5957691216*(x + 0.044715 x^3)).
// ---------------------------------------------------------------------------
__device__ __forceinline__ float gelu_fast(float v) {
    const float c1 = (float)(-2.0 * 0.7978845608028654 * 1.4426950408889634);
    const float c2 = c1 * 0.044715f;
    float v2 = v * v;
    float t  = fmaf(c2, v2, c1);
    float z  = v * t;
    float e  = fast_exp2(z);
    float r  = __builtin_amdgcn_rcpf(1.0f + e);
    return v * r;
}

__device__ __forceinline__ float ldz(const float* __restrict__ xb, int tt) {
    if (tt < 0 || tt >= T_LEN) return 0.0f;
    return xb[tt * C_LEN];
}

// ---------------------------------------------------------------------------
// Per-lane MFMA weight fragments for the conditioner MLP.
// Layer1 (K=32, k0..3 = [W1 rows 0..2, b1], rest zero):
//   b1a = hidden 0..15, b1b = hidden 16..31 (B-operand: col = lane&15,
//   k = 8*(lane>>4)+j — the standard CDNA4 16x16x32 B layout).
// Layer2: W2's K-rows permuted to the interleaved hidden order
//   canon(kk) = (kk&1)*16 + (kk>>1) so the gelu pack (h[n], h[n+16]) lands
//   as adjacent f16s in the H LDS rows. W2/b2 pre-scaled by LOG2E so the
//   softmax uses raw v_exp_f32.
// wraw layout: [0..95] W1(3x32), [96..127] b1, [128..287] W2(32x5), [288..292] b2
// ---------------------------------------------------------------------------
struct Frags { hfx8 b1a, b1b, b2; f32x4 c2; };

__device__ __forceinline__ Frags build_frags(const float* __restrict__ wraw, int lane) {
    Frags f;
    const int n = lane & 15, g = lane >> 4;
    hfx8 z = {0, 0, 0, 0, 0, 0, 0, 0};
    f.b1a = z; f.b1b = z;
    if (g == 0) {
        f.b1a[0] = (hf)wraw[n];      f.b1b[0] = (hf)wraw[16 + n];
        f.b1a[1] = (hf)wraw[32 + n]; f.b1b[1] = (hf)wraw[48 + n];
        f.b1a[2] = (hf)wraw[64 + n]; f.b1b[2] = (hf)wraw[80 + n];
        f.b1a[3] = (hf)wraw[96 + n]; f.b1b[3] = (hf)wraw[112 + n];
    }
#pragma unroll
    for (int j = 0; j < 8; ++j) {
        int kk = 8 * g + j;
        int canon = ((kk & 1) << 4) | (kk >> 1);
        float wv = (n < 5) ? wraw[128 + canon * 5 + n] * LOG2E : 0.0f;
        f.b2[j] = (hf)wv;
    }
    float cc = (n < 5) ? wraw[288 + n] * LOG2E : 0.0f;
    f.c2 = (f32x4){cc, cc, cc, cc};
    return f;
}

// ---------------------------------------------------------------------------
// Per-thread worker: one channel c, 4 consecutive t starting at t0.
// CHECKED=true handles series edges (zero-pad conv, reflect-pad pooling).
// Position id within a wave: p = m*64 + lane; tile t = p>>4, row = p&15.
// fe:  4KB per-wave; 256 rows x 16B, A-operand feats [mean,var,x,1,0...] f16.
// hb:  per-wave H buffer; 16 rows x HSTR bytes (64B payload), reused per tile.
// lgb: per-wave logit buffer; 256 positions x LSTR bytes (5 f16 logits).
// All LDS traffic is wave-private -> no barriers; DS ops are in-order/wave;
// lds_fence() stops compiler reordering at the cross-lane hand-off points.
// ---------------------------------------------------------------------------
template <bool CHECKED>
__device__ __forceinline__ void work(const float* __restrict__ x,
                                     float* __restrict__ out,
                                     const float* __restrict__ wraw,
                                     char* __restrict__ fe,
                                     char* __restrict__ hb,
                                     char* __restrict__ lgb,
                                     int b, int t0, int c, int lane) {
    const float* xb = x + (size_t)b * T_LEN * C_LEN + c;  // index by t*C_LEN

    // ---- pooling window values: x[t0-7 .. t0+11] (reflect at edges) ----
    float v[19];
#pragma unroll
    for (int i = 0; i < 19; ++i) {
        int tt = t0 - 7 + i;
        if (CHECKED) {
            tt = (tt < 0) ? -tt : tt;
            tt = (tt >= T_LEN) ? (2 * T_LEN - 2 - tt) : tt;
        }
        v[i] = xb[tt * C_LEN];
    }

    float mean[4], var[4], xc[4];
    {
        float s = 0.f, q = 0.f;
#pragma unroll
        for (int i = 0; i < 16; ++i) { s += v[i]; q = fmaf(v[i], v[i], q); }
#pragma unroll
        for (int m = 0; m < 4; ++m) {
            if (m > 0) {
                float nw = v[15 + m], od = v[m - 1];
                s = s + nw - od;
                q = fmaf(nw, nw, fmaf(od, -od, q));
            }
            mean[m] = s * 0.0625f;
            float m2 = q * 0.0625f;
            float vv = fmaf(-mean[m], mean[m], m2);
            var[m] = vv > 0.f ? vv : 0.f;
            xc[m]  = v[7 + m];
        }
    }

    // ---- stage feats rows into LDS (A-operand for layer1); mean/var regs
    // die here, keeping the conv-phase register peak at baseline level ----
#pragma unroll
    for (int m = 0; m < 4; ++m) {
        auto p0 = __builtin_amdgcn_cvt_pkrtz(mean[m], var[m]);
        auto p1 = __builtin_amdgcn_cvt_pkrtz(xc[m], 1.0f);
        int4 r4;
        r4.x = __builtin_bit_cast(int, p0);
        r4.y = __builtin_bit_cast(int, p1);
        r4.z = 0; r4.w = 0;
        *(int4*)(fe + (m * 64 + lane) * 16) = r4;
    }
    lds_fence();

    // ---- 5 Gaussian convs, symmetric-pair register sliding windows ----
    float acc[5][4];
#pragma unroll
    for (int k = 0; k < 5; ++k)
#pragma unroll
        for (int m = 0; m < 4; ++m) acc[k][m] = BANK.g[k][0] * xc[m];

    float F[4], Bw[4];
    if (CHECKED) {
        F[1] = ldz(xb, t0 + 1); F[2] = ldz(xb, t0 + 2);
        F[3] = ldz(xb, t0 + 3); F[0] = ldz(xb, t0 + 4);
        Bw[3] = ldz(xb, t0 - 1); Bw[0] = ldz(xb, t0);
        Bw[1] = ldz(xb, t0 + 1); Bw[2] = ldz(xb, t0 + 2);
    } else {
        F[1] = v[8]; F[2] = v[9]; F[3] = v[10]; F[0] = v[11];
        Bw[3] = v[6]; Bw[0] = v[7]; Bw[1] = v[8]; Bw[2] = v[9];
    }

#pragma unroll
    for (int j = 1; j <= 56; ++j) {
        float sm[4];
#pragma unroll
        for (int m = 0; m < 4; ++m)
            sm[m] = F[(j + m) & 3] + Bw[(m - j) & 3];
#pragma unroll
        for (int k = 0; k < 5; ++k) {
            if (j <= RAD[k]) {
#pragma unroll
                for (int m = 0; m < 4; ++m)
                    acc[k][m] = fmaf(BANK.g[k][j], sm[m], acc[k][m]);
            }
        }
        if (j < 56) {
            if (CHECKED) {
                F[j & 3]        = ldz(xb, t0 + j + 4);
                Bw[(3 - j) & 3] = ldz(xb, t0 - j - 1);
            } else {
                F[j & 3]        = (j <= 7) ? v[j + 11] : xb[(t0 + j + 4) * C_LEN];
                Bw[(3 - j) & 3] = (j <= 6) ? v[6 - j]  : xb[(t0 - j - 1) * C_LEN];
            }
        }
    }

    // ---- conditioner MLP on the matrix pipe: 16 tiles of 16 positions ----
    // Per tile: A1 read -> 2x mfma (layer1) -> gelu x8 -> pack to H ->
    //           A2 read -> 1x mfma (layer2, +b2*LOG2E via C) -> f16 logits.
    // Frags built here (after conv) so conv-phase VGPR peak is unchanged.
    Frags fr = build_frags(wraw, lane);
    const int rl = lane & 15, gq = lane >> 4;
    const char* a1p = fe + rl * 16;                     // + t*256 per tile
    char*       hwp = hb + gq * (4 * HSTR) + rl * 4;    // + r*HSTR per row
    const char* a2p = hb + rl * HSTR + gq * 16;
    char*       lwp = lgb + (4 * gq) * LSTR + rl * 2;   // + (t*16+r)*LSTR (rl<5)
    const f32x4 z4 = (f32x4){0.f, 0.f, 0.f, 0.f};

#pragma unroll 2
    for (int t = 0; t < 16; ++t) {
        hfx8 a1 = *(const hfx8*)(a1p + t * 256);
        f32x4 d1a = __builtin_amdgcn_mfma_f32_16x16x32_f16(a1, fr.b1a, z4, 0, 0, 0);
        f32x4 d1b = __builtin_amdgcn_mfma_f32_16x16x32_f16(a1, fr.b1b, z4, 0, 0, 0);
#pragma unroll
        for (int r = 0; r < 4; ++r) {
            auto hp = __builtin_amdgcn_cvt_pkrtz(gelu_fast(d1a[r]), gelu_fast(d1b[r]));
            *(int*)(hwp + r * HSTR) = __builtin_bit_cast(int, hp);
        }
        lds_fence();
        hfx8 a2 = *(const hfx8*)a2p;
        lds_fence();
        f32x4 d2 = __builtin_amdgcn_mfma_f32_16x16x32_f16(a2, fr.b2, fr.c2, 0, 0, 0);
        // C/D layout: col(=out k)=lane&15, row(=pos in tile)=4*(lane>>4)+r
        if (rl < 5) {
#pragma unroll
            for (int r = 0; r < 4; ++r)
                *(hf*)(lwp + (t * 16 + r) * LSTR) = (hf)d2[r];
        }
    }
    lds_fence();

    // ---- readback logits + softmax over K=5 (already x LOG2E; max-free:
    // |logit*log2e| is bounded << 127 so exp2 can't overflow) + mixture ----
#pragma unroll
    for (int m = 0; m < 4; ++m) {
        const char* Lr = lgb + (m * 64 + lane) * LSTR;   // bank 3*pos%32: 2-way
        int  w01 = *(const int*)(Lr);
        int  w23 = *(const int*)(Lr + 4);
        hf   q4  = *(const hf*)(Lr + 8);
        hfx2 q01 = __builtin_bit_cast(hfx2, w01);
        hfx2 q23 = __builtin_bit_cast(hfx2, w23);
        float e0 = fast_exp2((float)q01[0]);
        float e1 = fast_exp2((float)q01[1]);
        float e2 = fast_exp2((float)q23[0]);
        float e3 = fast_exp2((float)q23[1]);
        float e4 = fast_exp2((float)q4);
        float den = ((e0 + e1) + (e2 + e3)) + e4;
        float num = e0 * acc[0][m];
        num = fmaf(e1, acc[1][m], num);
        num = fmaf(e2, acc[2][m], num);
        num = fmaf(e3, acc[3][m], num);
        num = fmaf(e4, acc[4][m], num);
        out[((size_t)b * T_LEN + t0 + m) * C_LEN + c] = num * __builtin_amdgcn_rcpf(den);
    }
}

// ---------------------------------------------------------------------------
// Single fused kernel. Boundary chunks (28/1024 per b) take the CHECKED path.
// __launch_bounds__(256, 2): cap 256 regs/wave. Round-2 post-mortem: (256,4)
// capped at 128 total; with the MFMA accum split the conv phase got 64 arch
// VGPRs and spilled to scratch (WRITE_SIZE 65MB -> 3.3GB, 3x slowdown).
// ---------------------------------------------------------------------------
__global__ __launch_bounds__(256, 2) void agt_fused(
    const float* __restrict__ x, const float* __restrict__ W1,
    const float* __restrict__ b1, const float* __restrict__ W2,
    const float* __restrict__ b2, float* __restrict__ out) {
    __shared__ float wraw[296];
    __shared__ __align__(16) char fe_lds[4][4096];
    __shared__ __align__(16) char h_lds[4][16 * HSTR];
    __shared__ __align__(16) char lg_lds[4][256 * LSTR];

    int tid = threadIdx.x;
    for (int i = tid; i < 293; i += 256) {
        float w;
        if (i < 96)       w = W1[i];
        else if (i < 128) w = b1[i - 96];
        else if (i < 288) w = W2[i - 128];
        else              w = b2[i - 288];
        wraw[i] = w;
    }
    __syncthreads();

    int b     = blockIdx.x >> 10;        // 1024 chunks per batch
    int chunk = blockIdx.x & 1023;
    int t0    = chunk * 4;
    int lane  = tid & 63;
    char* fe  = &fe_lds[tid >> 6][0];
    char* hb  = &h_lds[tid >> 6][0];
    char* lgb = &lg_lds[tid >> 6][0];

    if (chunk >= 14 && chunk < 1010)
        work<false>(x, out, wraw, fe, hb, lgb, b, t0, tid, lane);
    else
        work<true>(x, out, wraw, fe, hb, lgb, b, t0, tid, lane);
}

extern "C" void kernel_launch(void* const* d_in, const int* in_sizes, int n_in,
                              void* d_out, int out_size, void* d_ws, size_t ws_size,
                              hipStream_t stream) {
    const float* x  = (const float*)d_in[0];
    const float* W1 = (const float*)d_in[1];
    const float* b1 = (const float*)d_in[2];
    const float* W2 = (const float*)d_in[3];
    const float* b2 = (const float*)d_in[4];
    float* out = (float*)d_out;

    (void)in_sizes; (void)n_in; (void)d_ws; (void)ws_size; (void)out_size;

    agt_fused<<<dim3(B_LEN * 1024), dim3(256), 0, stream>>>(x, W1, b1, W2, b2, out);
}

// Round 4
// 455.748 us; speedup vs baseline: 2.7708x; 1.0146x over previous
//
#include <hip/hip_runtime.h>
#include <math.h>

#define T_LEN 4096
#define C_LEN 256
#define B_LEN 16
#define LOG2E 1.4426950408889634f
#define HSTR 80          // H-buffer row stride in bytes (16B-aligned, non-pow2 banking)
#define HBUF (16 * HSTR) // one H tile buffer (16 rows)
#define LSTR 12          // logit buffer stride per position (bank = 3*pos % 32 -> 2-way)

// ---------------------------------------------------------------------------
// Compile-time Gaussian kernel bank (matches numpy: exp(-0.5*(j/s)^2), trunc
// at r=int(4*s), normalized by sum+1e-12). Values become instruction literals.
// ---------------------------------------------------------------------------
constexpr double cexp(double x) {
    double y = x * (1.0 / 1024.0);
    double t = 1.0, term = 1.0;
    for (int i = 1; i <= 12; ++i) { term *= y / i; t += term; }
    for (int i = 0; i < 10; ++i) t = t * t;   // ^1024
    return t;
}

constexpr int RAD[5] = {10, 16, 24, 36, 56};

struct Bank { float g[5][57]; };

constexpr Bank make_bank() {
    Bank b{};
    const double sig[5] = {2.5, 4.0, 6.0, 9.0, 14.0};
    for (int k = 0; k < 5; ++k) {
        double w[57] = {};
        for (int j = 0; j <= RAD[k]; ++j)
            w[j] = cexp(-0.5 * (double)(j * j) / (sig[k] * sig[k]));
        double s = w[0];
        for (int j = 1; j <= RAD[k]; ++j) s += 2.0 * w[j];
        s += 1e-12;
        for (int j = 0; j <= RAD[k]; ++j) b.g[k][j] = (float)(w[j] / s);
    }
    return b;
}

constexpr Bank BANK = make_bank();

typedef _Float16 hf;
typedef hf    hfx2 __attribute__((ext_vector_type(2)));
typedef hf    hfx8 __attribute__((ext_vector_type(8)));
typedef float f32x4 __attribute__((ext_vector_type(4)));

// Compiler-level memory fence (no instruction emitted). The MLP phase
// communicates across lanes through per-wave LDS with no barriers: hardware
// DS ops are in-order per wave; the fence only stops compiler reordering.
__device__ __forceinline__ void lds_fence() { asm volatile("" ::: "memory"); }

__device__ __forceinline__ float fast_exp2(float x) {
#if __has_builtin(__builtin_amdgcn_exp2f)
    return __builtin_amdgcn_exp2f(x);
#else
    return __expf(x * 0.6931471805599453f);
#endif
}

// ---------------------------------------------------------------------------
// Fast GELU (tanh form): x * sigmoid(1.5957691216*(x + 0.044715 x^3)).
// ---------------------------------------------------------------------------
__device__ __forceinline__ float gelu_fast(float v) {
    const float c1 = (float)(-2.0 * 0.7978845608028654 * 1.4426950408889634);
    const float c2 = c1 * 0.044715f;
    float v2 = v * v;
    float t  = fmaf(c2, v2, c1);
    float z  = v * t;
    float e  = fast_exp2(z);
    float r  = __builtin_amdgcn_rcpf(1.0f + e);
    return v * r;
}

__device__ __forceinline__ float ldz(const float* __restrict__ xb, int tt) {
    if (tt < 0 || tt >= T_LEN) return 0.0f;
    return xb[tt * C_LEN];
}

// ---------------------------------------------------------------------------
// Per-lane MFMA weight fragments for the conditioner MLP.
// Layer1 (K=32, k0..3 = [W1 rows 0..2, b1], rest zero):
//   b1a = hidden 0..15, b1b = hidden 16..31. Only g==0 lanes (k=0..3) are
//   nonzero -> A-frag garbage at k>=4 is multiplied by zero B rows.
// Layer2: W2's K-rows permuted to the interleaved hidden order
//   canon(kk) = (kk&1)*16 + (kk>>1) so the gelu pack (h[n], h[n+16]) lands
//   as adjacent f16s in the H LDS rows. W2/b2 pre-scaled by LOG2E so the
//   softmax uses raw v_exp_f32.
// wraw layout: [0..95] W1(3x32), [96..127] b1, [128..287] W2(32x5), [288..292] b2
// ---------------------------------------------------------------------------
struct Frags { hfx8 b1a, b1b, b2; f32x4 c2; };

__device__ __forceinline__ Frags build_frags(const float* __restrict__ wraw, int lane) {
    Frags f;
    const int n = lane & 15, g = lane >> 4;
    hfx8 z = {0, 0, 0, 0, 0, 0, 0, 0};
    f.b1a = z; f.b1b = z;
    if (g == 0) {
        f.b1a[0] = (hf)wraw[n];      f.b1b[0] = (hf)wraw[16 + n];
        f.b1a[1] = (hf)wraw[32 + n]; f.b1b[1] = (hf)wraw[48 + n];
        f.b1a[2] = (hf)wraw[64 + n]; f.b1b[2] = (hf)wraw[80 + n];
        f.b1a[3] = (hf)wraw[96 + n]; f.b1b[3] = (hf)wraw[112 + n];
    }
#pragma unroll
    for (int j = 0; j < 8; ++j) {
        int kk = 8 * g + j;
        int canon = ((kk & 1) << 4) | (kk >> 1);
        float wv = (n < 5) ? wraw[128 + canon * 5 + n] * LOG2E : 0.0f;
        f.b2[j] = (hf)wv;
    }
    float cc = (n < 5) ? wraw[288 + n] * LOG2E : 0.0f;
    f.c2 = (f32x4){cc, cc, cc, cc};
    return f;
}

// ---------------------------------------------------------------------------
// Per-thread worker: one channel c, 4 consecutive t starting at t0.
// CHECKED=true handles series edges (zero-pad conv, reflect-pad pooling).
// Position id within a wave: p = m*64 + lane; tile t = p>>4, row = p&15.
//
// MLP phase (matrix pipe), round-4 structure:
//  - A1 operand built via 2x ds_bpermute from register-packed feats
//    (pk0/pk1[m]); no feats LDS staging. Source lane for tile t row rl is
//    16*(t&3)+rl in m-group t>>2. Lanes>=16 fetch garbage that multiplies
//    zero B rows (k>=8), and int4{.z,.w}=0 covers k=4..7.
//  - H double-buffered (2 x 16 rows x HSTR); explicit 2-deep software
//    pipeline: iter t does a2read(t) early, then layer1(t+1) (mfma+gelu,
//    ~200cy of independent work hiding a2 latency), bperm issued 2 tiles
//    ahead (full-iteration latency hiding), then mfma2(t)+logit write.
//  - Round-3 post-mortem: a per-tile full fence serialized 2 DS round trips
//    x 16 tiles at ~1.8 waves/SIMD -> +60us stall. This schedule leaves >=1
//    iteration of work between every DS issue and its consumer.
// ---------------------------------------------------------------------------
template <bool CHECKED>
__device__ __forceinline__ void work(const float* __restrict__ x,
                                     float* __restrict__ out,
                                     const float* __restrict__ wraw,
                                     char* __restrict__ hb,
                                     char* __restrict__ lgb,
                                     int b, int t0, int c, int lane) {
    const float* xb = x + (size_t)b * T_LEN * C_LEN + c;  // index by t*C_LEN

    // ---- pooling window values: x[t0-7 .. t0+11] (reflect at edges) ----
    float v[19];
#pragma unroll
    for (int i = 0; i < 19; ++i) {
        int tt = t0 - 7 + i;
        if (CHECKED) {
            tt = (tt < 0) ? -tt : tt;
            tt = (tt >= T_LEN) ? (2 * T_LEN - 2 - tt) : tt;
        }
        v[i] = xb[tt * C_LEN];
    }

    float mean[4], var[4], xc[4];
    {
        float s = 0.f, q = 0.f;
#pragma unroll
        for (int i = 0; i < 16; ++i) { s += v[i]; q = fmaf(v[i], v[i], q); }
#pragma unroll
        for (int m = 0; m < 4; ++m) {
            if (m > 0) {
                float nw = v[15 + m], od = v[m - 1];
                s = s + nw - od;
                q = fmaf(nw, nw, fmaf(od, -od, q));
            }
            mean[m] = s * 0.0625f;
            float m2 = q * 0.0625f;
            float vv = fmaf(-mean[m], mean[m], m2);
            var[m] = vv > 0.f ? vv : 0.f;
            xc[m]  = v[7 + m];
        }
    }

    // ---- pack feats to registers (A1 source for ds_bpermute) ----
    int pk0[4], pk1[4];
#pragma unroll
    for (int m = 0; m < 4; ++m) {
        pk0[m] = __builtin_bit_cast(int, __builtin_amdgcn_cvt_pkrtz(mean[m], var[m]));
        pk1[m] = __builtin_bit_cast(int, __builtin_amdgcn_cvt_pkrtz(xc[m], 1.0f));
    }

    // ---- 5 Gaussian convs, symmetric-pair register sliding windows ----
    float acc[5][4];
#pragma unroll
    for (int k = 0; k < 5; ++k)
#pragma unroll
        for (int m = 0; m < 4; ++m) acc[k][m] = BANK.g[k][0] * xc[m];

    float F[4], Bw[4];
    if (CHECKED) {
        F[1] = ldz(xb, t0 + 1); F[2] = ldz(xb, t0 + 2);
        F[3] = ldz(xb, t0 + 3); F[0] = ldz(xb, t0 + 4);
        Bw[3] = ldz(xb, t0 - 1); Bw[0] = ldz(xb, t0);
        Bw[1] = ldz(xb, t0 + 1); Bw[2] = ldz(xb, t0 + 2);
    } else {
        F[1] = v[8]; F[2] = v[9]; F[3] = v[10]; F[0] = v[11];
        Bw[3] = v[6]; Bw[0] = v[7]; Bw[1] = v[8]; Bw[2] = v[9];
    }

#pragma unroll
    for (int j = 1; j <= 56; ++j) {
        float sm[4];
#pragma unroll
        for (int m = 0; m < 4; ++m)
            sm[m] = F[(j + m) & 3] + Bw[(m - j) & 3];
#pragma unroll
        for (int k = 0; k < 5; ++k) {
            if (j <= RAD[k]) {
#pragma unroll
                for (int m = 0; m < 4; ++m)
                    acc[k][m] = fmaf(BANK.g[k][j], sm[m], acc[k][m]);
            }
        }
        if (j < 56) {
            if (CHECKED) {
                F[j & 3]        = ldz(xb, t0 + j + 4);
                Bw[(3 - j) & 3] = ldz(xb, t0 - j - 1);
            } else {
                F[j & 3]        = (j <= 7) ? v[j + 11] : xb[(t0 + j + 4) * C_LEN];
                Bw[(3 - j) & 3] = (j <= 6) ? v[6 - j]  : xb[(t0 - j - 1) * C_LEN];
            }
        }
    }

    // ---- conditioner MLP on the matrix pipe: 16 tiles, software-pipelined ----
    Frags fr = build_frags(wraw, lane);
    const int rl  = lane & 15, gq = lane >> 4;
    const int rl4 = rl * 4;
    char* const hw_base = hb + gq * (4 * HSTR) + rl * 4;   // + buf*HBUF + r*HSTR
    const char* const a2_base = hb + rl * HSTR + gq * 16;  // + buf*HBUF
    char* const lwp = lgb + (4 * gq) * LSTR + rl * 2;      // + (t*16+r)*LSTR (rl<5)
    const f32x4 z4 = (f32x4){0.f, 0.f, 0.f, 0.f};

    int ib0[2], ib1[2];   // bperm results in flight (tiles t+1, t+2); static idx

    // Prologue: S0(0) + layer1(0) -> buf0, then S0(1).
    ib0[0] = __builtin_amdgcn_ds_bpermute(rl4, pk0[0]);
    ib1[0] = __builtin_amdgcn_ds_bpermute(rl4, pk1[0]);
    {
        int4 t4; t4.x = ib0[0]; t4.y = ib1[0]; t4.z = 0; t4.w = 0;
        hfx8 a1 = __builtin_bit_cast(hfx8, t4);
        f32x4 d1a = __builtin_amdgcn_mfma_f32_16x16x32_f16(a1, fr.b1a, z4, 0, 0, 0);
        f32x4 d1b = __builtin_amdgcn_mfma_f32_16x16x32_f16(a1, fr.b1b, z4, 0, 0, 0);
#pragma unroll
        for (int r = 0; r < 4; ++r) {
            auto hp = __builtin_amdgcn_cvt_pkrtz(gelu_fast(d1a[r]), gelu_fast(d1b[r]));
            *(int*)(hw_base + r * HSTR) = __builtin_bit_cast(int, hp);
        }
    }
    ib0[1] = __builtin_amdgcn_ds_bpermute(rl4 + 64, pk0[0]);
    ib1[1] = __builtin_amdgcn_ds_bpermute(rl4 + 64, pk1[0]);
    lds_fence();

#pragma unroll
    for (int t = 0; t < 16; ++t) {
        // S4(t): a2 read (program order after Hwrite(t); DS in-order per wave)
        hfx8 a2 = *(const hfx8*)(a2_base + (t & 1) * HBUF);

        // S1(t+1): mfma1 from bperm data issued a full iteration ago
        f32x4 d1a, d1b;
        if (t < 15) {
            const int j = t + 1;
            int4 t4; t4.x = ib0[j & 1]; t4.y = ib1[j & 1]; t4.z = 0; t4.w = 0;
            hfx8 a1 = __builtin_bit_cast(hfx8, t4);
            d1a = __builtin_amdgcn_mfma_f32_16x16x32_f16(a1, fr.b1a, z4, 0, 0, 0);
            d1b = __builtin_amdgcn_mfma_f32_16x16x32_f16(a1, fr.b1b, z4, 0, 0, 0);
        }

        // S0(t+2): issue bperms two tiles ahead (latency hidden by 1 full iter)
        if (t < 14) {
            const int j = t + 2;
            ib0[j & 1] = __builtin_amdgcn_ds_bpermute(rl4 + 64 * (j & 3), pk0[j >> 2]);
            ib1[j & 1] = __builtin_amdgcn_ds_bpermute(rl4 + 64 * (j & 3), pk1[j >> 2]);
        }

        // S2+S3(t+1): gelu + H write to the other buffer (hides a2(t) latency)
        if (t < 15) {
            const int j = t + 1;
            char* hw = hw_base + (j & 1) * HBUF;
#pragma unroll
            for (int r = 0; r < 4; ++r) {
                auto hp = __builtin_amdgcn_cvt_pkrtz(gelu_fast(d1a[r]), gelu_fast(d1b[r]));
                *(int*)(hw + r * HSTR) = __builtin_bit_cast(int, hp);
            }
        }
        lds_fence();

        // S5(t): layer2 mfma (a2 issued at top of iter, ~full iter of work since)
        f32x4 d2 = __builtin_amdgcn_mfma_f32_16x16x32_f16(a2, fr.b2, fr.c2, 0, 0, 0);

        // S6(t): logit write. C/D layout: col(=k)=lane&15, row=4*(lane>>4)+r
        if (rl < 5) {
#pragma unroll
            for (int r = 0; r < 4; ++r)
                *(hf*)(lwp + (t * 16 + r) * LSTR) = (hf)d2[r];
        }
    }
    lds_fence();

    // ---- readback logits + softmax over K=5 (already x LOG2E; max-free:
    // |logit*log2e| is bounded << 127 so exp2 can't overflow) + mixture ----
#pragma unroll
    for (int m = 0; m < 4; ++m) {
        const char* Lr = lgb + (m * 64 + lane) * LSTR;   // bank 3*pos%32: 2-way
        int  w01 = *(const int*)(Lr);
        int  w23 = *(const int*)(Lr + 4);
        hf   q4  = *(const hf*)(Lr + 8);
        hfx2 q01 = __builtin_bit_cast(hfx2, w01);
        hfx2 q23 = __builtin_bit_cast(hfx2, w23);
        float e0 = fast_exp2((float)q01[0]);
        float e1 = fast_exp2((float)q01[1]);
        float e2 = fast_exp2((float)q23[0]);
        float e3 = fast_exp2((float)q23[1]);
        float e4 = fast_exp2((float)q4);
        float den = ((e0 + e1) + (e2 + e3)) + e4;
        float num = e0 * acc[0][m];
        num = fmaf(e1, acc[1][m], num);
        num = fmaf(e2, acc[2][m], num);
        num = fmaf(e3, acc[3][m], num);
        num = fmaf(e4, acc[4][m], num);
        out[((size_t)b * T_LEN + t0 + m) * C_LEN + c] = num * __builtin_amdgcn_rcpf(den);
    }
}

// ---------------------------------------------------------------------------
// Single fused kernel. Boundary chunks (28/1024 per b) take the CHECKED path.
// __launch_bounds__(256, 2): Round-2 post-mortem — (256,4) halved the unified
// register file and spilled the conv phase to scratch (3x slowdown).
// ---------------------------------------------------------------------------
__global__ __launch_bounds__(256, 2) void agt_fused(
    const float* __restrict__ x, const float* __restrict__ W1,
    const float* __restrict__ b1, const float* __restrict__ W2,
    const float* __restrict__ b2, float* __restrict__ out) {
    __shared__ float wraw[296];
    __shared__ __align__(16) char h_lds[4][2 * HBUF];     // 2.5KB/wave, dbuf
    __shared__ __align__(16) char lg_lds[4][256 * LSTR];  // 3KB/wave

    int tid = threadIdx.x;
    for (int i = tid; i < 293; i += 256) {
        float w;
        if (i < 96)       w = W1[i];
        else if (i < 128) w = b1[i - 96];
        else if (i < 288) w = W2[i - 128];
        else              w = b2[i - 288];
        wraw[i] = w;
    }
    __syncthreads();

    int b     = blockIdx.x >> 10;        // 1024 chunks per batch
    int chunk = blockIdx.x & 1023;
    int t0    = chunk * 4;
    int lane  = tid & 63;
    char* hb  = &h_lds[tid >> 6][0];
    char* lgb = &lg_lds[tid >> 6][0];

    if (chunk >= 14 && chunk < 1010)
        work<false>(x, out, wraw, hb, lgb, b, t0, tid, lane);
    else
        work<true>(x, out, wraw, hb, lgb, b, t0, tid, lane);
}

extern "C" void kernel_launch(void* const* d_in, const int* in_sizes, int n_in,
                              void* d_out, int out_size, void* d_ws, size_t ws_size,
                              hipStream_t stream) {
    const float* x  = (const float*)d_in[0];
    const float* W1 = (const float*)d_in[1];
    const float* b1 = (const float*)d_in[2];
    const float* W2 = (const float*)d_in[3];
    const float* b2 = (const float*)d_in[4];
    float* out = (float*)d_out;

    (void)in_sizes; (void)n_in; (void)d_ws; (void)ws_size; (void)out_size;

    agt_fused<<<dim3(B_LEN * 1024), dim3(256), 0, stream>>>(x, W1, b1, W2, b2, out);
}

// Round 6
// 420.726 us; speedup vs baseline: 3.0015x; 1.0832x over previous
//
#include <hip/hip_runtime.h>
#include <math.h>

#define T_LEN 4096
#define C_LEN 256
#define B_LEN 16
#define LOG2E 1.4426950408889634f

// ---------------------------------------------------------------------------
// Compile-time Gaussian kernel bank (matches numpy: exp(-0.5*(j/s)^2), trunc
// at r=int(4*s), normalized by sum+1e-12). Values become instruction literals.
// ---------------------------------------------------------------------------
constexpr double cexp(double x) {
    double y = x * (1.0 / 1024.0);
    double t = 1.0, term = 1.0;
    for (int i = 1; i <= 12; ++i) { term *= y / i; t += term; }
    for (int i = 0; i < 10; ++i) t = t * t;   // ^1024
    return t;
}

constexpr int RAD[5] = {10, 16, 24, 36, 56};

struct Bank { float g[5][57]; };

constexpr Bank make_bank() {
    Bank b{};
    const double sig[5] = {2.5, 4.0, 6.0, 9.0, 14.0};
    for (int k = 0; k < 5; ++k) {
        double w[57] = {};
        for (int j = 0; j <= RAD[k]; ++j)
            w[j] = cexp(-0.5 * (double)(j * j) / (sig[k] * sig[k]));
        double s = w[0];
        for (int j = 1; j <= RAD[k]; ++j) s += 2.0 * w[j];
        s += 1e-12;
        for (int j = 0; j <= RAD[k]; ++j) b.g[k][j] = (float)(w[j] / s);
    }
    return b;
}

constexpr Bank BANK = make_bank();

typedef _Float16 hf;
typedef hf     hfx2  __attribute__((ext_vector_type(2)));  // arithmetic type
typedef __fp16 fp16x2 __attribute__((ext_vector_type(2))); // builtin ABI type

__device__ __forceinline__ float fast_exp2(float x) {
#if __has_builtin(__builtin_amdgcn_exp2f)
    return __builtin_amdgcn_exp2f(x);
#else
    return __expf(x * 0.6931471805599453f);
#endif
}

__device__ __forceinline__ hf exp2h(hf x) {
#if __has_builtin(__builtin_amdgcn_exp2h)
    return __builtin_amdgcn_exp2h(x);
#else
    return (hf)__builtin_amdgcn_exp2f((float)x);
#endif
}

__device__ __forceinline__ hf rcph(hf x) {
#if __has_builtin(__builtin_amdgcn_rcph)
    return __builtin_amdgcn_rcph(x);
#else
    return (hf)__builtin_amdgcn_rcpf((float)x);
#endif
}

// 2-wide f16 dot with f32 accumulate: v_dot2_f32_f16 (1 inst = 2 MACs).
// bit_cast at the builtin boundary: clang's builtin signature uses __fp16
// vectors, which do not implicitly convert from _Float16 vectors (round-5
// compile failure).
__device__ __forceinline__ float fdot2(hfx2 a, hfx2 b, float c) {
#if __has_builtin(__builtin_amdgcn_fdot2)
    return __builtin_amdgcn_fdot2(__builtin_bit_cast(fp16x2, a),
                                  __builtin_bit_cast(fp16x2, b), c, false);
#else
    return fmaf((float)a[1], (float)b[1], fmaf((float)a[0], (float)b[0], c));
#endif
}

__device__ __forceinline__ hfx2 pk2(float a, float b) {
    return __builtin_bit_cast(hfx2, __builtin_amdgcn_cvt_pkrtz(a, b));
}

__device__ __forceinline__ float ldz(const float* __restrict__ xb, int tt) {
    if (tt < 0 || tt >= T_LEN) return 0.0f;
    return xb[tt * C_LEN];
}

// ---------------------------------------------------------------------------
// Per-thread worker: one channel c, 4 consecutive t starting at t0.
// CHECKED=true handles series edges (zero-pad conv, reflect-pad pooling).
//
// Round-6 structure: conv/pool/softmax identical to the proven 385us round-0
// kernel. The conditioner MLP processes HIDDEN UNITS IN PAIRS with packed-f16
// register math (v_pk_fma_f16 pre + gelu head, f16 transcendental tail,
// v_dot2_f32_f16 logit accumulate -> f32 logits, same precision as round-0).
// No LDS round-trips, no cross-lane ops (rounds 1-4 post-mortem: every MFMA
// offload lost 30-65us to operand marshalling at ~1.8 waves/SIMD).
// wpk[p][0..8]: pair p = hidden units (2p, 2p+1), all weights f16-packed;
// [0..3] = W1 rows 0..2 + b1, [4..8] = W2 cols 0..4 (x log2e). Uniform LDS
// reads -> broadcast, no bank conflicts.
// ---------------------------------------------------------------------------
template <bool CHECKED>
__device__ __forceinline__ void work(const float* __restrict__ x,
                                     float* __restrict__ out,
                                     const int (*__restrict__ wpk)[12],
                                     const float* __restrict__ b2l,
                                     int b, int t0, int c) {
    const float* xb = x + (size_t)b * T_LEN * C_LEN + c;  // index by t*C_LEN

    // ---- pooling window values: x[t0-7 .. t0+11] (reflect at edges) ----
    float v[19];
#pragma unroll
    for (int i = 0; i < 19; ++i) {
        int tt = t0 - 7 + i;
        if (CHECKED) {
            tt = (tt < 0) ? -tt : tt;
            tt = (tt >= T_LEN) ? (2 * T_LEN - 2 - tt) : tt;
        }
        v[i] = xb[tt * C_LEN];
    }

    float mean[4], var[4], xc[4];
    {
        float s = 0.f, q = 0.f;
#pragma unroll
        for (int i = 0; i < 16; ++i) { s += v[i]; q = fmaf(v[i], v[i], q); }
#pragma unroll
        for (int m = 0; m < 4; ++m) {
            if (m > 0) {
                float nw = v[15 + m], od = v[m - 1];
                s = s + nw - od;
                q = fmaf(nw, nw, fmaf(od, -od, q));
            }
            mean[m] = s * 0.0625f;
            float m2 = q * 0.0625f;
            float vv = fmaf(-mean[m], mean[m], m2);
            var[m] = vv > 0.f ? vv : 0.f;
            xc[m]  = v[7 + m];   // x[t0+m] (always in range -> reflect is identity)
        }
    }

    // ---- duplicate-packed feats for the packed-pair MLP ----
    hfx2 meanP[4], varP[4], xcP[4];
#pragma unroll
    for (int m = 0; m < 4; ++m) {
        meanP[m] = pk2(mean[m], mean[m]);
        varP[m]  = pk2(var[m],  var[m]);
        xcP[m]   = pk2(xc[m],   xc[m]);
    }

    // ---- 5 Gaussian convs, symmetric-pair register sliding windows ----
    float acc[5][4];
#pragma unroll
    for (int k = 0; k < 5; ++k)
#pragma unroll
        for (int m = 0; m < 4; ++m) acc[k][m] = BANK.g[k][0] * xc[m];

    float F[4], Bw[4];
    if (CHECKED) {
        F[1] = ldz(xb, t0 + 1); F[2] = ldz(xb, t0 + 2);
        F[3] = ldz(xb, t0 + 3); F[0] = ldz(xb, t0 + 4);
        Bw[3] = ldz(xb, t0 - 1); Bw[0] = ldz(xb, t0);
        Bw[1] = ldz(xb, t0 + 1); Bw[2] = ldz(xb, t0 + 2);
    } else {
        F[1] = v[8]; F[2] = v[9]; F[3] = v[10]; F[0] = v[11];
        Bw[3] = v[6]; Bw[0] = v[7]; Bw[1] = v[8]; Bw[2] = v[9];
    }

#pragma unroll
    for (int j = 1; j <= 56; ++j) {
        float sm[4];
#pragma unroll
        for (int m = 0; m < 4; ++m)
            sm[m] = F[(j + m) & 3] + Bw[(m - j) & 3];
#pragma unroll
        for (int k = 0; k < 5; ++k) {
            if (j <= RAD[k]) {
#pragma unroll
                for (int m = 0; m < 4; ++m)
                    acc[k][m] = fmaf(BANK.g[k][j], sm[m], acc[k][m]);
            }
        }
        if (j < 56) {
            if (CHECKED) {
                F[j & 3]        = ldz(xb, t0 + j + 4);
                Bw[(3 - j) & 3] = ldz(xb, t0 - j - 1);
            } else {
                F[j & 3]        = (j <= 7) ? v[j + 11] : xb[(t0 + j + 4) * C_LEN];
                Bw[(3 - j) & 3] = (j <= 6) ? v[6 - j]  : xb[(t0 - j - 1) * C_LEN];
            }
        }
    }

    // ---- conditioner MLP: 16 hidden-unit pairs, packed-f16 register math ----
    float lg[5][4];
#pragma unroll
    for (int k = 0; k < 5; ++k) {
        float bk = b2l[k];
#pragma unroll
        for (int m = 0; m < 4; ++m) lg[k][m] = bk;
    }

    // gelu tanh-form constants (pre-scaled by log2e), duplicated in f16
    const float c1f = (float)(-2.0 * 0.7978845608028654 * 1.4426950408889634);
    const hfx2 C1P = {(hf)c1f, (hf)c1f};
    const hfx2 C2P = {(hf)(c1f * 0.044715f), (hf)(c1f * 0.044715f)};
    const hfx2 ONE = {(hf)1.0f, (hf)1.0f};

#pragma unroll 2
    for (int p = 0; p < 16; ++p) {
        const int4 wA = *(const int4*)&wpk[p][0];   // w1r0, w1r1, w1r2, b1
        const int4 wB = *(const int4*)&wpk[p][4];   // w2 cols 0..3 (x log2e)
        const int  w4 = wpk[p][8];                  // w2 col 4    (x log2e)
        const hfx2 w10 = __builtin_bit_cast(hfx2, wA.x);
        const hfx2 w11 = __builtin_bit_cast(hfx2, wA.y);
        const hfx2 w12 = __builtin_bit_cast(hfx2, wA.z);
        const hfx2 bbp = __builtin_bit_cast(hfx2, wA.w);
        const hfx2 w20 = __builtin_bit_cast(hfx2, wB.x);
        const hfx2 w21 = __builtin_bit_cast(hfx2, wB.y);
        const hfx2 w22 = __builtin_bit_cast(hfx2, wB.z);
        const hfx2 w23 = __builtin_bit_cast(hfx2, wB.w);
        const hfx2 w24 = __builtin_bit_cast(hfx2, w4);
#pragma unroll
        for (int m = 0; m < 4; ++m) {
            hfx2 pre = bbp;
            pre = w10 * meanP[m] + pre;   // v_pk_fma_f16
            pre = w11 * varP[m]  + pre;
            pre = w12 * xcP[m]   + pre;
            // fast GELU, f16: v * sigmoid(1.5957691*(v + 0.044715 v^3));
            // exp2h(+inf)=inf -> rcp=0 -> h=0 (saturation exact)
            hfx2 v2 = pre * pre;
            hfx2 tt = v2 * C2P + C1P;
            hfx2 zz = pre * tt;
            hfx2 ee; ee[0] = exp2h(zz[0]); ee[1] = exp2h(zz[1]);
            hfx2 dd = ee + ONE;
            hfx2 rr; rr[0] = rcph(dd[0]); rr[1] = rcph(dd[1]);
            hfx2 hh = pre * rr;
            lg[0][m] = fdot2(hh, w20, lg[0][m]);   // v_dot2_f32_f16
            lg[1][m] = fdot2(hh, w21, lg[1][m]);
            lg[2][m] = fdot2(hh, w22, lg[2][m]);
            lg[3][m] = fdot2(hh, w23, lg[3][m]);
            lg[4][m] = fdot2(hh, w24, lg[4][m]);
        }
    }

    // ---- softmax over K=5 (logits already x log2e) + mixture, store ----
#pragma unroll
    for (int m = 0; m < 4; ++m) {
        float l0 = lg[0][m], l1 = lg[1][m], l2 = lg[2][m], l3 = lg[3][m], l4 = lg[4][m];
        float mx = fmaxf(fmaxf(fmaxf(l0, l1), fmaxf(l2, l3)), l4);
        float e0 = fast_exp2(l0 - mx), e1 = fast_exp2(l1 - mx), e2 = fast_exp2(l2 - mx);
        float e3 = fast_exp2(l3 - mx), e4 = fast_exp2(l4 - mx);
        float den = ((e0 + e1) + (e2 + e3)) + e4;
        float num = e0 * acc[0][m];
        num = fmaf(e1, acc[1][m], num);
        num = fmaf(e2, acc[2][m], num);
        num = fmaf(e3, acc[3][m], num);
        num = fmaf(e4, acc[4][m], num);
        out[((size_t)b * T_LEN + t0 + m) * C_LEN + c] = num * __builtin_amdgcn_rcpf(den);
    }
}

// ---------------------------------------------------------------------------
// Single fused kernel: boundary chunks (28/1024 per b) take the CHECKED path,
// block-uniform branch. Weight staging: 16 pairs x 9 packed dwords (768B LDS),
// built by threads 0..15; all MLP-phase reads are wave-uniform broadcasts.
// __launch_bounds__(256) plain — round-2 post-mortem: (256,4) halves the
// unified register file and spills the conv phase to scratch (3x slowdown).
// ---------------------------------------------------------------------------
__global__ __launch_bounds__(256) void agt_fused(
    const float* __restrict__ x, const float* __restrict__ W1,
    const float* __restrict__ b1, const float* __restrict__ W2,
    const float* __restrict__ b2, float* __restrict__ out) {
    __shared__ __align__(16) int wpk[16][12];
    __shared__ float b2l[5];
    {
        int tid = threadIdx.x;
        if (tid < 16) {
            const int h0 = 2 * tid, h1 = 2 * tid + 1;
            wpk[tid][0] = __builtin_bit_cast(int, pk2(W1[h0],      W1[h1]));
            wpk[tid][1] = __builtin_bit_cast(int, pk2(W1[32 + h0], W1[32 + h1]));
            wpk[tid][2] = __builtin_bit_cast(int, pk2(W1[64 + h0], W1[64 + h1]));
            wpk[tid][3] = __builtin_bit_cast(int, pk2(b1[h0],      b1[h1]));
#pragma unroll
            for (int k = 0; k < 5; ++k)
                wpk[tid][4 + k] = __builtin_bit_cast(
                    int, pk2(W2[h0 * 5 + k] * LOG2E, W2[h1 * 5 + k] * LOG2E));
            wpk[tid][9] = wpk[tid][10] = wpk[tid][11] = 0;
        }
        if (tid < 5) b2l[tid] = b2[tid] * LOG2E;
        __syncthreads();
    }
    int b     = blockIdx.x >> 10;        // 1024 chunks per batch
    int chunk = blockIdx.x & 1023;
    int t0    = chunk * 4;
    if (chunk >= 14 && chunk < 1010)
        work<false>(x, out, wpk, b2l, b, t0, threadIdx.x);
    else
        work<true>(x, out, wpk, b2l, b, t0, threadIdx.x);
}

extern "C" void kernel_launch(void* const* d_in, const int* in_sizes, int n_in,
                              void* d_out, int out_size, void* d_ws, size_t ws_size,
                              hipStream_t stream) {
    const float* x  = (const float*)d_in[0];
    const float* W1 = (const float*)d_in[1];
    const float* b1 = (const float*)d_in[2];
    const float* W2 = (const float*)d_in[3];
    const float* b2 = (const float*)d_in[4];
    float* out = (float*)d_out;

    (void)in_sizes; (void)n_in; (void)d_ws; (void)ws_size; (void)out_size;

    agt_fused<<<dim3(B_LEN * 1024), dim3(256), 0, stream>>>(x, W1, b1, W2, b2, out);
}